// Round 5
// baseline (259.173 us; speedup 1.0000x reference)
//
#include <hip/hip_runtime.h>
#include <hip/hip_cooperative_groups.h>
#include <math.h>

namespace cg = cooperative_groups;

#define KPTS 512
#define VOX (64*64*64)
#define NBLK 4096            // 16x16x16 NMS blocks per instance
#define SLOTS 4              // deterministic winner slots per NMS block
#define NCAND (NBLK * SLOTS) // 16384
#define NSEL 1024
#define GRID 512

typedef unsigned long long u64;
typedef unsigned int u32;

typedef float f2v __attribute__((ext_vector_type(2)));
typedef f2v f2a __attribute__((aligned(4)));   // 8B vector load at 4B alignment

// f32 op-sequence sigmoid with correctly-rounded expf (via double):
// t = rn(exp(-x)); s = 1/(1+t)  -- mimics NumPy f32 semantics.
__device__ __forceinline__ float ref_sigmoid(float x) {
  float t = (float)exp(-(double)x);
  float d = 1.0f + t;
  return 1.0f / d;
}

__device__ __forceinline__ void emit_pt(int inst, u64 key, u32 rank,
                                        int* __restrict__ pts,
                                        float* __restrict__ out) {
  u32 idx = ~(u32)key;                    // 0xFFFFFFFF - low
  pts[inst * KPTS + rank] = (int)idx;
  int x = idx & 63, y = (idx >> 6) & 63, z = (int)(idx >> 12);
  float gx = ((float)x * 2.0f) / 63.0f - 1.0f;
  float gy = ((float)y * 2.0f) / 63.0f - 1.0f;
  float gz = ((float)z * 2.0f) / 63.0f - 1.0f;
  int m = inst >> 1, b = inst & 1;
  float* g = out + (size_t)m * 3072 + (size_t)(b * KPTS + rank) * 3;
  g[0] = gx; g[1] = gy; g[2] = gz;
}

// Whole pipeline in one cooperative kernel: NMS -> top-512 -> sample -> match.
// 512 blocks x 256 threads; 3 grid syncs. LDS is a reused 17.7KB arena.
__global__ void __launch_bounds__(256, 2) fused_all(
    const float* __restrict__ k1, const float* __restrict__ k2,
    const float* __restrict__ f1, const float* __restrict__ f2,
    const float* __restrict__ fc_w, const float* __restrict__ fc_b,
    float* __restrict__ out, u64* __restrict__ cands, int* __restrict__ pts,
    float* __restrict__ norms, float* __restrict__ desc)
{
  cg::grid_group grid = cg::this_grid();
  __shared__ __align__(16) char smem[17664];
  int bid = blockIdx.x, tid = threadIdx.x;

  // ===== stage 1: sigmoid + 4x4x4 NMS, deterministic candidate slots =====
  {
    float (*sm)[16] = (float (*)[16])smem;        // 256B
    u32* wcnt = (u32*)(smem + 256);               // 64B
    for (int u = bid; u < 1024; u += GRID) {      // 2 strip-units per block
      int strip = u & 255, inst = u >> 8;
      const float* vol = ((inst >> 1) ? k2 : k1) + (size_t)(inst & 1) * VOX;
      __syncthreads();                            // LDS reuse across iters
      if (tid < 16) wcnt[tid] = 0;
      int x = tid & 63, yl = tid >> 6;
      int yb = strip & 15, zb = strip >> 4;
      int y = yb * 4 + yl, z0 = zb * 4;
      float s[4];
      #pragma unroll
      for (int zl = 0; zl < 4; zl++)
        s[zl] = ref_sigmoid(vol[((z0 + zl) << 12) | (y << 6) | x]);
      float m = fmaxf(fmaxf(s[0], s[1]), fmaxf(s[2], s[3]));
      m = fmaxf(m, __shfl_xor(m, 1));
      m = fmaxf(m, __shfl_xor(m, 2));             // max over 4x * 1y * 4z
      if ((x & 3) == 0) sm[yl][x >> 2] = m;
      __syncthreads();
      int xb = x >> 2;
      float bm = fmaxf(fmaxf(sm[0][xb], sm[1][xb]), fmaxf(sm[2][xb], sm[3][xb]));
      int nb = ((zb * 16 + yb) << 4) | xb;
      u64* slot = cands + (size_t)inst * NCAND + (size_t)nb * SLOTS;
      #pragma unroll
      for (int zl = 0; zl < 4; zl++) {
        if (s[zl] == bm) {                        // winner (ties all emitted)
          u32 r = atomicAdd(&wcnt[xb], 1u);       // LDS atomic, ~1/block
          if (r < SLOTS) {
            int addr = ((z0 + zl) << 12) | (y << 6) | x;
            slot[r] = ((u64)__float_as_uint(s[zl]) << 32) | (u64)(0xFFFFFFFFu - (u32)addr);
          }
        }
      }
      __syncthreads();
      if (tid < 16 * SLOTS) {                     // zero unused slots
        int xb2 = tid >> 2, k = tid & 3;
        if ((u32)k >= wcnt[xb2])
          cands[(size_t)inst * NCAND + (size_t)(((zb * 16 + yb) << 4) | xb2) * SLOTS + k] = 0;
      }
    }
  }
  grid.sync();

  // ===== stage 2: per-instance top-512 (histogram prune + rank) =====
  if (bid < 4) {
    int inst = bid;
    u64* sel   = (u64*)smem;                      // 8192B
    u32* hist  = (u32*)(smem + 8192);             // 1024B
    u32* selCnt = (u32*)(smem + 9216);
    int* bstar = (int*)(smem + 9220);
    hist[tid] = 0;
    if (tid == 0) *selCnt = 0;
    __syncthreads();
    const u64* cb = cands + (size_t)inst * NCAND;
    // 256 value-ordered bins: sigmoid in [0.5,1) -> mantissa bits [22:15]
    for (u32 i = tid; i < NCAND; i += 256) {
      u64 key = cb[i];
      if (!key) continue;
      u32 vb = (u32)(key >> 32);
      int bin = (vb >= 0x3F800000u) ? 255 : ((vb < 0x3F000000u) ? 0 : (int)((vb >> 15) & 0xFF));
      atomicAdd(&hist[bin], 1u);
    }
    __syncthreads();
    if (tid == 0) {
      u32 cum = 0; int b = 255;
      for (; b >= 0; b--) { cum += hist[b]; if (cum >= KPTS) break; }
      *bstar = (b < 0) ? 0 : b;
    }
    __syncthreads();
    int B = *bstar;
    int lane = tid & 63;
    for (u32 i = tid; i < NCAND; i += 256) {
      u64 key = cb[i];
      bool pred = false;
      if (key) {
        u32 vb = (u32)(key >> 32);
        int bin = (vb >= 0x3F800000u) ? 255 : ((vb < 0x3F000000u) ? 0 : (int)((vb >> 15) & 0xFF));
        pred = (bin >= B);
      }
      u64 wmask = __ballot(pred);                 // wave-aggregated append
      if (wmask) {
        u32 cnt = (u32)__popcll(wmask);
        int leader = __ffsll((long long)wmask) - 1;
        u32 base = 0;
        if (lane == leader) base = atomicAdd(selCnt, cnt);
        base = __shfl(base, leader);
        if (pred) {
          u32 off = (u32)__popcll(wmask & ((1ull << lane) - 1ull));
          u32 p = base + off;
          if (p < NSEL) sel[p] = key;
        }
      }
    }
    __syncthreads();
    u32 sc = *selCnt; if (sc > NSEL) sc = NSEL;
    // rank by broadcast scan: (value desc, idx asc) == u64 desc; keys unique
    u64 m0 = (tid < sc) ? sel[tid] : 0ull;
    u64 m1 = (tid + 256 < sc) ? sel[tid + 256] : 0ull;
    u64 m2 = (tid + 512 < sc) ? sel[tid + 512] : 0ull;
    u64 m3 = (tid + 768 < sc) ? sel[tid + 768] : 0ull;
    u32 r0 = 0, r1 = 0, r2 = 0, r3 = 0;
    for (u32 i = 0; i < sc; i++) {
      u64 v = sel[i];                             // LDS broadcast (same addr)
      r0 += (v > m0); r1 += (v > m1); r2 += (v > m2); r3 += (v > m3);
    }
    if (tid < sc && r0 < KPTS) emit_pt(inst, m0, r0, pts, out);
    if (tid + 256 < sc && r1 < KPTS) emit_pt(inst, m1, r1, pts, out);
    if (tid + 512 < sc && r2 < KPTS) emit_pt(inst, m2, r2, pts, out);
    if (tid + 768 < sc && r3 < KPTS) emit_pt(inst, m3, r3, pts, out);
  }
  grid.sync();

  // ===== stage 3: trilinear sampling, one wave per (inst, point) =====
  {
    int w = bid * 4 + (tid >> 6);                 // 0..2047
    int inst = w >> 9, kp = w & 511;
    int m = inst >> 1, b = inst & 1;
    int lane = tid & 63;                          // channel 0..63
    int idx = pts[inst * KPTS + kp];
    int x = idx & 63, y = (idx >> 6) & 63, z = idx >> 12;
    float gx = ((float)x * 2.0f) / 63.0f - 1.0f;
    float gy = ((float)y * 2.0f) / 63.0f - 1.0f;
    float gz = ((float)z * 2.0f) / 63.0f - 1.0f;
    float ix = ((gx + 1.0f) * 64.0f - 1.0f) * 0.5f;
    float iy = ((gy + 1.0f) * 64.0f - 1.0f) * 0.5f;
    float iz = ((gz + 1.0f) * 64.0f - 1.0f) * 0.5f;
    float x0f = floorf(ix), y0f = floorf(iy), z0f = floorf(iz);
    float fx = ix - x0f, fy = iy - y0f, fz = iz - z0f;
    int x0 = (int)x0f, y0 = (int)y0f, z0 = (int)z0f;
    int xc = x0 < 0 ? 0 : (x0 > 62 ? 62 : x0);
    bool xlo = (x0 == xc);
    float wx0 = (x0 >= 0) ? (1.0f - fx) : 0.0f;
    float wx1 = (x0 <= 62) ? fx : 0.0f;
    int yc0 = y0 < 0 ? 0 : y0, yc1 = (y0 + 1) > 63 ? 63 : (y0 + 1);
    int zc0 = z0 < 0 ? 0 : z0, zc1 = (z0 + 1) > 63 ? 63 : (z0 + 1);
    float wy0 = (y0 >= 0) ? (1.0f - fy) : 0.0f;
    float wy1 = ((y0 + 1) <= 63) ? fy : 0.0f;
    float wz0 = (z0 >= 0) ? (1.0f - fz) : 0.0f;
    float wz1 = ((z0 + 1) <= 63) ? fz : 0.0f;

    const float* fv = (m ? f2 : f1) + ((size_t)b * 64 + lane) * VOX;
    float acc = 0.0f;
    #pragma unroll
    for (int dz = 0; dz < 2; dz++) {
      int zz = dz ? zc1 : zc0; float wzz = dz ? wz1 : wz0;
      #pragma unroll
      for (int dy = 0; dy < 2; dy++) {
        int yy = dy ? yc1 : yc0; float wyy = dy ? wy1 : wy0;
        f2a v = *reinterpret_cast<const f2a*>(fv + ((zz << 12) | (yy << 6) | xc));
        float v0 = xlo ? v.x : v.y;
        float v1 = xlo ? v.y : v.x;
        acc = fmaf(wzz * wyy, fmaf(v0, wx0, v1 * wx1), acc);
      }
    }
    desc[((size_t)inst * KPTS + kp) * 64 + lane] = acc;   // coalesced
    float ss = acc * acc;
    #pragma unroll
    for (int o = 32; o; o >>= 1) ss += __shfl_xor(ss, o);
    const float* kv = (m ? k2 : k1) + (size_t)b * VOX;
    float part = 0.0f;
    if (lane < 4) {
      int dz = lane >> 1, dy = lane & 1;
      int zz = dz ? zc1 : zc0; float wzz = dz ? wz1 : wz0;
      int yy = dy ? yc1 : yc0; float wyy = dy ? wy1 : wy0;
      f2a v = *reinterpret_cast<const f2a*>(kv + ((zz << 12) | (yy << 6) | xc));
      float v0 = xlo ? v.x : v.y;
      float v1 = xlo ? v.y : v.x;
      part = wzz * wyy * fmaf(v0, wx0, v1 * wx1);
    }
    part += __shfl_xor(part, 1);
    part += __shfl_xor(part, 2);
    if (lane == 0) {
      norms[inst * KPTS + kp] = sqrtf(ss);
      out[6144 + m * 1024 + b * KPTS + kp] = part;
    }
  }
  grid.sync();

  // ===== stage 4: matcher, one 32x32 (i,j) tile per block =====
  {
    float (*e0t)[68] = (float (*)[68])smem;             // 8704B
    float (*e1t)[68] = (float (*)[68])(smem + 8704);    // 8704B
    float* n1s = (float*)(smem + 17408);                // 128B
    float* n2s = (float*)(smem + 17536);                // 128B
    int b = bid >> 8, ti = (bid >> 4) & 15, tj = bid & 15;
    int i0 = ti * 32, j0 = tj * 32;
    const float* d1 = desc + (size_t)b * KPTS * 64;
    const float* d2 = desc + (size_t)(2 + b) * KPTS * 64;
    __syncthreads();                                    // LDS arena reuse
    {
      int row = tid >> 3, ci = (tid & 7) * 8;
      const float4* dp = (const float4*)(d1 + (size_t)(i0 + row) * 64 + ci);
      const float4* wp0 = (const float4*)(fc_w + ci);
      const float4* wp1 = (const float4*)(fc_w + 64 + ci);
      float4 va = dp[0], vb = dp[1];
      float4 w0a = wp0[0], w0b = wp0[1], w1a = wp1[0], w1b = wp1[1];
      float4* e0p = (float4*)&e0t[row][ci];
      float4* e1p = (float4*)&e1t[row][ci];
      e0p[0] = make_float4(va.x * w0a.x, va.y * w0a.y, va.z * w0a.z, va.w * w0a.w);
      e0p[1] = make_float4(vb.x * w0b.x, vb.y * w0b.y, vb.z * w0b.z, vb.w * w0b.w);
      e1p[0] = make_float4(va.x * w1a.x, va.y * w1a.y, va.z * w1a.z, va.w * w1a.w);
      e1p[1] = make_float4(vb.x * w1b.x, vb.y * w1b.y, vb.z * w1b.z, vb.w * w1b.w);
    }
    if (tid < 32) n1s[tid] = norms[b * KPTS + i0 + tid];
    else if (tid < 64) n2s[tid - 32] = norms[(2 + b) * KPTS + j0 + (tid - 32)];
    int j = tid & 31, r0w = tid >> 5;
    float4 d2r[16];
    const float* drow = d2 + (size_t)(j0 + j) * 64;
    #pragma unroll
    for (int q = 0; q < 16; q++) d2r[q] = *(const float4*)(drow + q * 4);
    __syncthreads();
    float bb0 = fc_b[0], bb1 = fc_b[1];
    float n2 = n2s[j];
    #pragma unroll
    for (int r = 0; r < 4; r++) {
      int i = r0w + r * 8;
      float s0 = 0.0f, s1 = 0.0f;
      #pragma unroll
      for (int q = 0; q < 16; q++) {
        float4 E0 = *(const float4*)&e0t[i][q * 4];
        float4 E1 = *(const float4*)&e1t[i][q * 4];
        float4 D = d2r[q];
        s0 = fmaf(E0.x, D.x, s0); s0 = fmaf(E0.y, D.y, s0);
        s0 = fmaf(E0.z, D.z, s0); s0 = fmaf(E0.w, D.w, s0);
        s1 = fmaf(E1.x, D.x, s1); s1 = fmaf(E1.y, D.y, s1);
        s1 = fmaf(E1.z, D.z, s1); s1 = fmaf(E1.w, D.w, s1);
      }
      int gi = i0 + i, gj = j0 + j;
      size_t row = ((size_t)(b * KPTS + gi)) * KPTS + gj;
      *(float2*)(out + 8192 + row * 2) = make_float2(s0 + bb0, s1 + bb1);
      float n1 = n1s[i];
      out[1056768 + row] = n1 * fabsf(1.0f / (1e-6f + n1) - 1.0f / (1e-6f + n2));
    }
  }
}

extern "C" void kernel_launch(void* const* d_in, const int* in_sizes, int n_in,
                              void* d_out, int out_size, void* d_ws, size_t ws_size,
                              hipStream_t stream) {
  const float* k1 = (const float*)d_in[0];
  const float* k2 = (const float*)d_in[1];
  const float* f1 = (const float*)d_in[2];
  const float* f2 = (const float*)d_in[3];
  const float* fw = (const float*)d_in[4];
  const float* fb = (const float*)d_in[5];
  float* out = (float*)d_out;
  char* ws = (char*)d_ws;
  // ws: cands(4*16384*8B=512KB) | pts(8KB) | norms(8KB) | desc(4*512*64*4B=512KB)
  u64* cands   = (u64*)ws;
  int* pts     = (int*)(ws + 524288);
  float* norms = (float*)(ws + 524288 + 8192);
  float* desc  = (float*)(ws + 524288 + 8192 + 8192);

  void* args[] = { (void*)&k1, (void*)&k2, (void*)&f1, (void*)&f2,
                   (void*)&fw, (void*)&fb, (void*)&out,
                   (void*)&cands, (void*)&pts, (void*)&norms, (void*)&desc };
  hipLaunchCooperativeKernel((const void*)fused_all, dim3(GRID), dim3(256),
                             args, 0, stream);
}

// Round 6
// 164.962 us; speedup vs baseline: 1.5711x; 1.5711x over previous
//
#include <hip/hip_runtime.h>
#include <math.h>

#define KPTS 512
#define VOX (64*64*64)
#define NBLK 4096            // 16x16x16 NMS blocks per instance
#define SLOTS 4              // deterministic winner slots per NMS block
#define NCAND (NBLK * SLOTS) // 16384
#define NSEL 1024
#define GRID 512
#define NGRP 16
#define GSZ (GRID / NGRP)    // 32 blocks per arrival group

typedef unsigned long long u64;
typedef unsigned int u32;

typedef float f2v __attribute__((ext_vector_type(2)));
typedef f2v f2a __attribute__((aligned(4)));   // 8B vector load at 4B alignment

// f32 op-sequence sigmoid with correctly-rounded expf (via double):
// t = rn(exp(-x)); s = 1/(1+t)  -- mimics NumPy f32 semantics.
__device__ __forceinline__ float ref_sigmoid(float x) {
  float t = (float)exp(-(double)x);
  float d = 1.0f + t;
  return 1.0f / d;
}

// Hierarchical device barrier. bar layout (u32, 64B stride):
//   [(p*NGRP+g)*16] group counters, [(3*NGRP+p)*16] roots. Zeroed per launch
//   by a memset node. Arrivals: 32 RMWs/group on distinct lines (~1.5us);
//   spin is a relaxed agent-scope LOAD (no RMW serialization) + s_sleep.
__device__ __forceinline__ void grid_barrier(u32* bar, int phase, int bid) {
  __syncthreads();
  if (threadIdx.x == 0) {
    __threadfence();                                       // release
    u32* gcnt = bar + (phase * NGRP + (bid & (NGRP - 1))) * 16;
    u32* root = bar + (3 * NGRP + phase) * 16;
    u32 r = atomicAdd(gcnt, 1u);
    if (r == GSZ - 1) {
      __threadfence();                                     // cover group's stores
      atomicAdd(root, 1u);
    }
    while (__hip_atomic_load(root, __ATOMIC_RELAXED, __HIP_MEMORY_SCOPE_AGENT) < NGRP)
      __builtin_amdgcn_s_sleep(2);
    __threadfence();                                       // acquire
  }
  __syncthreads();
}

__device__ __forceinline__ void emit_pt(int inst, u64 key, u32 rank,
                                        int* __restrict__ pts,
                                        float* __restrict__ out) {
  u32 idx = ~(u32)key;                    // 0xFFFFFFFF - low
  pts[inst * KPTS + rank] = (int)idx;
  int x = idx & 63, y = (idx >> 6) & 63, z = (int)(idx >> 12);
  float gx = ((float)x * 2.0f) / 63.0f - 1.0f;
  float gy = ((float)y * 2.0f) / 63.0f - 1.0f;
  float gz = ((float)z * 2.0f) / 63.0f - 1.0f;
  int m = inst >> 1, b = inst & 1;
  float* g = out + (size_t)m * 3072 + (size_t)(b * KPTS + rank) * 3;
  g[0] = gx; g[1] = gy; g[2] = gz;
}

// Whole pipeline in one cooperative kernel: NMS -> top-512 -> sample -> match.
// 512 blocks x 256 threads; 3 custom hierarchical barriers (not cg::sync).
__global__ void __launch_bounds__(256, 2) fused_all(
    const float* __restrict__ k1, const float* __restrict__ k2,
    const float* __restrict__ f1, const float* __restrict__ f2,
    const float* __restrict__ fc_w, const float* __restrict__ fc_b,
    float* __restrict__ out, u64* __restrict__ cands, int* __restrict__ pts,
    float* __restrict__ norms, float* __restrict__ desc, u32* __restrict__ bar)
{
  __shared__ __align__(16) char smem[17664];
  int bid = blockIdx.x, tid = threadIdx.x;

  // ===== stage 1: sigmoid + 4x4x4 NMS, deterministic candidate slots =====
  {
    float (*sm)[16] = (float (*)[16])smem;        // 256B
    u32* wcnt = (u32*)(smem + 256);               // 64B
    for (int u = bid; u < 1024; u += GRID) {      // 2 strip-units per block
      int strip = u & 255, inst = u >> 8;
      const float* vol = ((inst >> 1) ? k2 : k1) + (size_t)(inst & 1) * VOX;
      __syncthreads();                            // LDS reuse across iters
      if (tid < 16) wcnt[tid] = 0;
      int x = tid & 63, yl = tid >> 6;
      int yb = strip & 15, zb = strip >> 4;
      int y = yb * 4 + yl, z0 = zb * 4;
      float s[4];
      #pragma unroll
      for (int zl = 0; zl < 4; zl++)
        s[zl] = ref_sigmoid(vol[((z0 + zl) << 12) | (y << 6) | x]);
      float m = fmaxf(fmaxf(s[0], s[1]), fmaxf(s[2], s[3]));
      m = fmaxf(m, __shfl_xor(m, 1));
      m = fmaxf(m, __shfl_xor(m, 2));             // max over 4x * 1y * 4z
      if ((x & 3) == 0) sm[yl][x >> 2] = m;
      __syncthreads();
      int xb = x >> 2;
      float bm = fmaxf(fmaxf(sm[0][xb], sm[1][xb]), fmaxf(sm[2][xb], sm[3][xb]));
      int nb = ((zb * 16 + yb) << 4) | xb;
      u64* slot = cands + (size_t)inst * NCAND + (size_t)nb * SLOTS;
      #pragma unroll
      for (int zl = 0; zl < 4; zl++) {
        if (s[zl] == bm) {                        // winner (ties all emitted)
          u32 r = atomicAdd(&wcnt[xb], 1u);       // LDS atomic, ~1/block
          if (r < SLOTS) {
            int addr = ((z0 + zl) << 12) | (y << 6) | x;
            slot[r] = ((u64)__float_as_uint(s[zl]) << 32) | (u64)(0xFFFFFFFFu - (u32)addr);
          }
        }
      }
      __syncthreads();
      if (tid < 16 * SLOTS) {                     // zero unused slots
        int xb2 = tid >> 2, k = tid & 3;
        if ((u32)k >= wcnt[xb2])
          cands[(size_t)inst * NCAND + (size_t)(((zb * 16 + yb) << 4) | xb2) * SLOTS + k] = 0;
      }
    }
  }
  grid_barrier(bar, 0, bid);

  // ===== stage 2: per-instance top-512 (histogram prune + rank) =====
  if (bid < 4) {
    int inst = bid;
    u64* sel   = (u64*)smem;                      // 8192B
    u32* hist  = (u32*)(smem + 8192);             // 1024B
    u32* selCnt = (u32*)(smem + 9216);
    int* bstar = (int*)(smem + 9220);
    hist[tid] = 0;
    if (tid == 0) *selCnt = 0;
    __syncthreads();
    const u64* cb = cands + (size_t)inst * NCAND;
    // 256 value-ordered bins: sigmoid in [0.5,1) -> mantissa bits [22:15]
    for (u32 i = tid; i < NCAND; i += 256) {
      u64 key = cb[i];
      if (!key) continue;
      u32 vb = (u32)(key >> 32);
      int bin = (vb >= 0x3F800000u) ? 255 : ((vb < 0x3F000000u) ? 0 : (int)((vb >> 15) & 0xFF));
      atomicAdd(&hist[bin], 1u);
    }
    __syncthreads();
    if (tid == 0) {
      u32 cum = 0; int b = 255;
      for (; b >= 0; b--) { cum += hist[b]; if (cum >= KPTS) break; }
      *bstar = (b < 0) ? 0 : b;
    }
    __syncthreads();
    int B = *bstar;
    int lane = tid & 63;
    for (u32 i = tid; i < NCAND; i += 256) {
      u64 key = cb[i];
      bool pred = false;
      if (key) {
        u32 vb = (u32)(key >> 32);
        int bin = (vb >= 0x3F800000u) ? 255 : ((vb < 0x3F000000u) ? 0 : (int)((vb >> 15) & 0xFF));
        pred = (bin >= B);
      }
      u64 wmask = __ballot(pred);                 // wave-aggregated append
      if (wmask) {
        u32 cnt = (u32)__popcll(wmask);
        int leader = __ffsll((long long)wmask) - 1;
        u32 base = 0;
        if (lane == leader) base = atomicAdd(selCnt, cnt);
        base = __shfl(base, leader);
        if (pred) {
          u32 off = (u32)__popcll(wmask & ((1ull << lane) - 1ull));
          u32 p = base + off;
          if (p < NSEL) sel[p] = key;
        }
      }
    }
    __syncthreads();
    u32 sc = *selCnt; if (sc > NSEL) sc = NSEL;
    // rank by broadcast scan: (value desc, idx asc) == u64 desc; keys unique
    u64 m0 = (tid < sc) ? sel[tid] : 0ull;
    u64 m1 = (tid + 256 < sc) ? sel[tid + 256] : 0ull;
    u64 m2 = (tid + 512 < sc) ? sel[tid + 512] : 0ull;
    u64 m3 = (tid + 768 < sc) ? sel[tid + 768] : 0ull;
    u32 r0 = 0, r1 = 0, r2 = 0, r3 = 0;
    for (u32 i = 0; i < sc; i++) {
      u64 v = sel[i];                             // LDS broadcast (same addr)
      r0 += (v > m0); r1 += (v > m1); r2 += (v > m2); r3 += (v > m3);
    }
    if (tid < sc && r0 < KPTS) emit_pt(inst, m0, r0, pts, out);
    if (tid + 256 < sc && r1 < KPTS) emit_pt(inst, m1, r1, pts, out);
    if (tid + 512 < sc && r2 < KPTS) emit_pt(inst, m2, r2, pts, out);
    if (tid + 768 < sc && r3 < KPTS) emit_pt(inst, m3, r3, pts, out);
  }
  grid_barrier(bar, 1, bid);

  // ===== stage 3: trilinear sampling, one wave per (inst, point) =====
  {
    int w = bid * 4 + (tid >> 6);                 // 0..2047
    int inst = w >> 9, kp = w & 511;
    int m = inst >> 1, b = inst & 1;
    int lane = tid & 63;                          // channel 0..63
    int idx = pts[inst * KPTS + kp];
    int x = idx & 63, y = (idx >> 6) & 63, z = idx >> 12;
    float gx = ((float)x * 2.0f) / 63.0f - 1.0f;
    float gy = ((float)y * 2.0f) / 63.0f - 1.0f;
    float gz = ((float)z * 2.0f) / 63.0f - 1.0f;
    float ix = ((gx + 1.0f) * 64.0f - 1.0f) * 0.5f;
    float iy = ((gy + 1.0f) * 64.0f - 1.0f) * 0.5f;
    float iz = ((gz + 1.0f) * 64.0f - 1.0f) * 0.5f;
    float x0f = floorf(ix), y0f = floorf(iy), z0f = floorf(iz);
    float fx = ix - x0f, fy = iy - y0f, fz = iz - z0f;
    int x0 = (int)x0f, y0 = (int)y0f, z0 = (int)z0f;
    int xc = x0 < 0 ? 0 : (x0 > 62 ? 62 : x0);
    bool xlo = (x0 == xc);
    float wx0 = (x0 >= 0) ? (1.0f - fx) : 0.0f;
    float wx1 = (x0 <= 62) ? fx : 0.0f;
    int yc0 = y0 < 0 ? 0 : y0, yc1 = (y0 + 1) > 63 ? 63 : (y0 + 1);
    int zc0 = z0 < 0 ? 0 : z0, zc1 = (z0 + 1) > 63 ? 63 : (z0 + 1);
    float wy0 = (y0 >= 0) ? (1.0f - fy) : 0.0f;
    float wy1 = ((y0 + 1) <= 63) ? fy : 0.0f;
    float wz0 = (z0 >= 0) ? (1.0f - fz) : 0.0f;
    float wz1 = ((z0 + 1) <= 63) ? fz : 0.0f;

    const float* fv = (m ? f2 : f1) + ((size_t)b * 64 + lane) * VOX;
    float acc = 0.0f;
    #pragma unroll
    for (int dz = 0; dz < 2; dz++) {
      int zz = dz ? zc1 : zc0; float wzz = dz ? wz1 : wz0;
      #pragma unroll
      for (int dy = 0; dy < 2; dy++) {
        int yy = dy ? yc1 : yc0; float wyy = dy ? wy1 : wy0;
        f2a v = *reinterpret_cast<const f2a*>(fv + ((zz << 12) | (yy << 6) | xc));
        float v0 = xlo ? v.x : v.y;
        float v1 = xlo ? v.y : v.x;
        acc = fmaf(wzz * wyy, fmaf(v0, wx0, v1 * wx1), acc);
      }
    }
    desc[((size_t)inst * KPTS + kp) * 64 + lane] = acc;   // coalesced
    float ss = acc * acc;
    #pragma unroll
    for (int o = 32; o; o >>= 1) ss += __shfl_xor(ss, o);
    const float* kv = (m ? k2 : k1) + (size_t)b * VOX;
    float part = 0.0f;
    if (lane < 4) {
      int dz = lane >> 1, dy = lane & 1;
      int zz = dz ? zc1 : zc0; float wzz = dz ? wz1 : wz0;
      int yy = dy ? yc1 : yc0; float wyy = dy ? wy1 : wy0;
      f2a v = *reinterpret_cast<const f2a*>(kv + ((zz << 12) | (yy << 6) | xc));
      float v0 = xlo ? v.x : v.y;
      float v1 = xlo ? v.y : v.x;
      part = wzz * wyy * fmaf(v0, wx0, v1 * wx1);
    }
    part += __shfl_xor(part, 1);
    part += __shfl_xor(part, 2);
    if (lane == 0) {
      norms[inst * KPTS + kp] = sqrtf(ss);
      out[6144 + m * 1024 + b * KPTS + kp] = part;
    }
  }
  grid_barrier(bar, 2, bid);

  // ===== stage 4: matcher, one 32x32 (i,j) tile per block =====
  {
    float (*e0t)[68] = (float (*)[68])smem;             // 8704B
    float (*e1t)[68] = (float (*)[68])(smem + 8704);    // 8704B
    float* n1s = (float*)(smem + 17408);                // 128B
    float* n2s = (float*)(smem + 17536);                // 128B
    int b = bid >> 8, ti = (bid >> 4) & 15, tj = bid & 15;
    int i0 = ti * 32, j0 = tj * 32;
    const float* d1 = desc + (size_t)b * KPTS * 64;
    const float* d2 = desc + (size_t)(2 + b) * KPTS * 64;
    {
      int row = tid >> 3, ci = (tid & 7) * 8;
      const float4* dp = (const float4*)(d1 + (size_t)(i0 + row) * 64 + ci);
      const float4* wp0 = (const float4*)(fc_w + ci);
      const float4* wp1 = (const float4*)(fc_w + 64 + ci);
      float4 va = dp[0], vb = dp[1];
      float4 w0a = wp0[0], w0b = wp0[1], w1a = wp1[0], w1b = wp1[1];
      float4* e0p = (float4*)&e0t[row][ci];
      float4* e1p = (float4*)&e1t[row][ci];
      e0p[0] = make_float4(va.x * w0a.x, va.y * w0a.y, va.z * w0a.z, va.w * w0a.w);
      e0p[1] = make_float4(vb.x * w0b.x, vb.y * w0b.y, vb.z * w0b.z, vb.w * w0b.w);
      e1p[0] = make_float4(va.x * w1a.x, va.y * w1a.y, va.z * w1a.z, va.w * w1a.w);
      e1p[1] = make_float4(vb.x * w1b.x, vb.y * w1b.y, vb.z * w1b.z, vb.w * w1b.w);
    }
    if (tid < 32) n1s[tid] = norms[b * KPTS + i0 + tid];
    else if (tid < 64) n2s[tid - 32] = norms[(2 + b) * KPTS + j0 + (tid - 32)];
    int j = tid & 31, r0w = tid >> 5;
    float4 d2r[16];
    const float* drow = d2 + (size_t)(j0 + j) * 64;
    #pragma unroll
    for (int q = 0; q < 16; q++) d2r[q] = *(const float4*)(drow + q * 4);
    __syncthreads();
    float bb0 = fc_b[0], bb1 = fc_b[1];
    float n2 = n2s[j];
    #pragma unroll
    for (int r = 0; r < 4; r++) {
      int i = r0w + r * 8;
      float s0 = 0.0f, s1 = 0.0f;
      #pragma unroll
      for (int q = 0; q < 16; q++) {
        float4 E0 = *(const float4*)&e0t[i][q * 4];
        float4 E1 = *(const float4*)&e1t[i][q * 4];
        float4 D = d2r[q];
        s0 = fmaf(E0.x, D.x, s0); s0 = fmaf(E0.y, D.y, s0);
        s0 = fmaf(E0.z, D.z, s0); s0 = fmaf(E0.w, D.w, s0);
        s1 = fmaf(E1.x, D.x, s1); s1 = fmaf(E1.y, D.y, s1);
        s1 = fmaf(E1.z, D.z, s1); s1 = fmaf(E1.w, D.w, s1);
      }
      int gi = i0 + i, gj = j0 + j;
      size_t row = ((size_t)(b * KPTS + gi)) * KPTS + gj;
      *(float2*)(out + 8192 + row * 2) = make_float2(s0 + bb0, s1 + bb1);
      float n1 = n1s[i];
      out[1056768 + row] = n1 * fabsf(1.0f / (1e-6f + n1) - 1.0f / (1e-6f + n2));
    }
  }
}

extern "C" void kernel_launch(void* const* d_in, const int* in_sizes, int n_in,
                              void* d_out, int out_size, void* d_ws, size_t ws_size,
                              hipStream_t stream) {
  const float* k1 = (const float*)d_in[0];
  const float* k2 = (const float*)d_in[1];
  const float* f1 = (const float*)d_in[2];
  const float* f2 = (const float*)d_in[3];
  const float* fw = (const float*)d_in[4];
  const float* fb = (const float*)d_in[5];
  float* out = (float*)d_out;
  char* ws = (char*)d_ws;
  // ws: cands(512KB) | pts(8KB) | norms(8KB) | desc(512KB) | barrier(4KB)
  u64* cands   = (u64*)ws;
  int* pts     = (int*)(ws + 524288);
  float* norms = (float*)(ws + 524288 + 8192);
  float* desc  = (float*)(ws + 524288 + 8192 + 8192);
  u32* bar     = (u32*)(ws + 1064960);

  hipMemsetAsync(bar, 0, 4096, stream);   // zero barrier counters each replay

  void* args[] = { (void*)&k1, (void*)&k2, (void*)&f1, (void*)&f2,
                   (void*)&fw, (void*)&fb, (void*)&out,
                   (void*)&cands, (void*)&pts, (void*)&norms, (void*)&desc,
                   (void*)&bar };
  hipLaunchCooperativeKernel((const void*)fused_all, dim3(GRID), dim3(256),
                             args, 0, stream);
}

// Round 7
// 109.064 us; speedup vs baseline: 2.3763x; 1.5125x over previous
//
#include <hip/hip_runtime.h>
#include <math.h>

#define KPTS 512
#define VOX (64*64*64)
#define NBLK 4096            // 16x16x16 NMS blocks per instance
#define SLOTS 4              // deterministic winner slots per NMS block
#define NCAND (NBLK * SLOTS) // 16384
#define NSEL 1024
#define GRID 512
#define NGRP 16
#define GSZ (GRID / NGRP)    // 32 blocks per arrival group

typedef unsigned long long u64;
typedef unsigned int u32;

typedef float f2v __attribute__((ext_vector_type(2)));
typedef f2v f2a __attribute__((aligned(4)));   // 8B vector load at 4B alignment

// ---- agent-scope coherent (L2-bypassing, LLC-coherent) accessors ----
__device__ __forceinline__ void cst64(u64* p, u64 v) {
  __hip_atomic_store(p, v, __ATOMIC_RELAXED, __HIP_MEMORY_SCOPE_AGENT);
}
__device__ __forceinline__ u64 cld64(const u64* p) {
  return __hip_atomic_load(p, __ATOMIC_RELAXED, __HIP_MEMORY_SCOPE_AGENT);
}
__device__ __forceinline__ void cst32(u32* p, u32 v) {
  __hip_atomic_store(p, v, __ATOMIC_RELAXED, __HIP_MEMORY_SCOPE_AGENT);
}
__device__ __forceinline__ u32 cld32(const u32* p) {
  return __hip_atomic_load(p, __ATOMIC_RELAXED, __HIP_MEMORY_SCOPE_AGENT);
}
__device__ __forceinline__ void cstf(float* p, float v) { cst32((u32*)p, __float_as_uint(v)); }
__device__ __forceinline__ float cldf(const float* p) { return __uint_as_float(cld32((const u32*)p)); }

// f32 op-sequence sigmoid with correctly-rounded expf (via double):
// t = rn(exp(-x)); s = 1/(1+t)  -- mimics NumPy f32 semantics.
__device__ __forceinline__ float ref_sigmoid(float x) {
  float t = (float)exp(-(double)x);
  float d = 1.0f + t;
  return 1.0f / d;
}

// Fence-free hierarchical grid barrier. All cross-stage data moves through
// agent-coherent accesses, so no L2 writeback/invalidate is needed here.
// __syncthreads() drains each thread's vmem (compiler emits s_waitcnt
// vmcnt(0) before s_barrier), so all block stores are at the coherence
// point before thread 0 signals arrival.
// bar layout (u32 words, 64B stride): gcnt[p][g] @ (p*16+g)*16,
// root[p] @ (48+p)*16, gdone[p][g] @ (64+p*16+g)*16. Zeroed per replay.
__device__ __forceinline__ void grid_barrier(u32* bar, int phase, int bid) {
  __syncthreads();
  if (threadIdx.x == 0) {
    int g = bid & (NGRP - 1);
    u32 r = __hip_atomic_fetch_add(bar + (phase * NGRP + g) * 16, 1u,
                                   __ATOMIC_RELAXED, __HIP_MEMORY_SCOPE_AGENT);
    if (r == GSZ - 1)
      __hip_atomic_fetch_add(bar + (48 + phase) * 16, 1u,
                             __ATOMIC_RELAXED, __HIP_MEMORY_SCOPE_AGENT);
    if (bid < NGRP) {                     // announcer for group g == bid
      while (__hip_atomic_load(bar + (48 + phase) * 16, __ATOMIC_RELAXED,
                               __HIP_MEMORY_SCOPE_AGENT) < NGRP)
        __builtin_amdgcn_s_sleep(8);
      cst32(bar + (64 + phase * NGRP + g) * 16, 1u);
    } else {                              // <=31 spinners per gdone line
      while (__hip_atomic_load(bar + (64 + phase * NGRP + g) * 16,
                               __ATOMIC_RELAXED, __HIP_MEMORY_SCOPE_AGENT) == 0u)
        __builtin_amdgcn_s_sleep(8);
    }
  }
  __syncthreads();
}

__device__ __forceinline__ void emit_pt(int inst, u64 key, u32 rank,
                                        int* __restrict__ pts,
                                        float* __restrict__ out) {
  u32 idx = ~(u32)key;                    // 0xFFFFFFFF - low
  cst32((u32*)(pts + inst * KPTS + rank), idx);
  int x = idx & 63, y = (idx >> 6) & 63, z = (int)(idx >> 12);
  float gx = ((float)x * 2.0f) / 63.0f - 1.0f;
  float gy = ((float)y * 2.0f) / 63.0f - 1.0f;
  float gz = ((float)z * 2.0f) / 63.0f - 1.0f;
  int m = inst >> 1, b = inst & 1;
  float* g = out + (size_t)m * 3072 + (size_t)(b * KPTS + rank) * 3;
  g[0] = gx; g[1] = gy; g[2] = gz;        // out: host-read only, plain stores
}

// Whole pipeline in one cooperative kernel: NMS -> top-512 -> sample -> match.
// 512 blocks x 256 threads; 3 fence-free barriers.
__global__ void __launch_bounds__(256, 2) fused_all(
    const float* __restrict__ k1, const float* __restrict__ k2,
    const float* __restrict__ f1, const float* __restrict__ f2,
    const float* __restrict__ fc_w, const float* __restrict__ fc_b,
    float* __restrict__ out, u64* __restrict__ cands, int* __restrict__ pts,
    float* __restrict__ norms, float* __restrict__ desc, u32* __restrict__ bar)
{
  __shared__ __align__(16) char smem[26624];
  int bid = blockIdx.x, tid = threadIdx.x;

  // ===== stage 1: sigmoid + 4x4x4 NMS, deterministic candidate slots =====
  {
    float (*sm)[16] = (float (*)[16])smem;        // 256B
    u32* wcnt = (u32*)(smem + 256);               // 64B
    for (int u = bid; u < 1024; u += GRID) {      // 2 strip-units per block
      int strip = u & 255, inst = u >> 8;
      const float* vol = ((inst >> 1) ? k2 : k1) + (size_t)(inst & 1) * VOX;
      __syncthreads();                            // LDS reuse across iters
      if (tid < 16) wcnt[tid] = 0;
      int x = tid & 63, yl = tid >> 6;
      int yb = strip & 15, zb = strip >> 4;
      int y = yb * 4 + yl, z0 = zb * 4;
      float s[4];
      #pragma unroll
      for (int zl = 0; zl < 4; zl++)
        s[zl] = ref_sigmoid(vol[((z0 + zl) << 12) | (y << 6) | x]);
      float m = fmaxf(fmaxf(s[0], s[1]), fmaxf(s[2], s[3]));
      m = fmaxf(m, __shfl_xor(m, 1));
      m = fmaxf(m, __shfl_xor(m, 2));             // max over 4x * 1y * 4z
      if ((x & 3) == 0) sm[yl][x >> 2] = m;
      __syncthreads();
      int xb = x >> 2;
      float bm = fmaxf(fmaxf(sm[0][xb], sm[1][xb]), fmaxf(sm[2][xb], sm[3][xb]));
      int nb = ((zb * 16 + yb) << 4) | xb;
      u64* slot = cands + (size_t)inst * NCAND + (size_t)nb * SLOTS;
      #pragma unroll
      for (int zl = 0; zl < 4; zl++) {
        if (s[zl] == bm) {                        // winner (ties all emitted)
          u32 r = atomicAdd(&wcnt[xb], 1u);       // LDS atomic, ~1/block
          if (r < SLOTS) {
            int addr = ((z0 + zl) << 12) | (y << 6) | x;
            cst64(&slot[r], ((u64)__float_as_uint(s[zl]) << 32) | (u64)(0xFFFFFFFFu - (u32)addr));
          }
        }
      }
      __syncthreads();
      if (tid < 16 * SLOTS) {                     // zero unused slots
        int xb2 = tid >> 2, k = tid & 3;
        if ((u32)k >= wcnt[xb2])
          cst64(&cands[(size_t)inst * NCAND + (size_t)(((zb * 16 + yb) << 4) | xb2) * SLOTS + k], 0ull);
      }
    }
  }
  grid_barrier(bar, 0, bid);

  // ===== stage 2: per-instance top-512 (histogram prune + rank) =====
  if (bid < 4) {
    int inst = bid;
    u64* sel   = (u64*)smem;                      // 8192B
    u32* hist  = (u32*)(smem + 8192);             // 1024B
    u32* selCnt = (u32*)(smem + 9216);
    int* bstar = (int*)(smem + 9220);
    hist[tid] = 0;
    if (tid == 0) *selCnt = 0;
    __syncthreads();
    const u64* cb = cands + (size_t)inst * NCAND;
    // 256 value-ordered bins: sigmoid in [0.5,1) -> mantissa bits [22:15]
    for (u32 i = tid; i < NCAND; i += 256) {
      u64 key = cld64(cb + i);
      if (!key) continue;
      u32 vb = (u32)(key >> 32);
      int bin = (vb >= 0x3F800000u) ? 255 : ((vb < 0x3F000000u) ? 0 : (int)((vb >> 15) & 0xFF));
      atomicAdd(&hist[bin], 1u);
    }
    __syncthreads();
    if (tid == 0) {
      u32 cum = 0; int b = 255;
      for (; b >= 0; b--) { cum += hist[b]; if (cum >= KPTS) break; }
      *bstar = (b < 0) ? 0 : b;
    }
    __syncthreads();
    int B = *bstar;
    int lane = tid & 63;
    for (u32 i = tid; i < NCAND; i += 256) {
      u64 key = cld64(cb + i);
      bool pred = false;
      if (key) {
        u32 vb = (u32)(key >> 32);
        int bin = (vb >= 0x3F800000u) ? 255 : ((vb < 0x3F000000u) ? 0 : (int)((vb >> 15) & 0xFF));
        pred = (bin >= B);
      }
      u64 wmask = __ballot(pred);                 // wave-aggregated append
      if (wmask) {
        u32 cnt = (u32)__popcll(wmask);
        int leader = __ffsll((long long)wmask) - 1;
        u32 base = 0;
        if (lane == leader) base = atomicAdd(selCnt, cnt);
        base = __shfl(base, leader);
        if (pred) {
          u32 off = (u32)__popcll(wmask & ((1ull << lane) - 1ull));
          u32 p = base + off;
          if (p < NSEL) sel[p] = key;
        }
      }
    }
    __syncthreads();
    u32 sc = *selCnt; if (sc > NSEL) sc = NSEL;
    // rank by broadcast scan: (value desc, idx asc) == u64 desc; keys unique
    u64 m0 = (tid < sc) ? sel[tid] : 0ull;
    u64 m1 = (tid + 256 < sc) ? sel[tid + 256] : 0ull;
    u64 m2 = (tid + 512 < sc) ? sel[tid + 512] : 0ull;
    u64 m3 = (tid + 768 < sc) ? sel[tid + 768] : 0ull;
    u32 r0 = 0, r1 = 0, r2 = 0, r3 = 0;
    for (u32 i = 0; i < sc; i++) {
      u64 v = sel[i];                             // LDS broadcast (same addr)
      r0 += (v > m0); r1 += (v > m1); r2 += (v > m2); r3 += (v > m3);
    }
    if (tid < sc && r0 < KPTS) emit_pt(inst, m0, r0, pts, out);
    if (tid + 256 < sc && r1 < KPTS) emit_pt(inst, m1, r1, pts, out);
    if (tid + 512 < sc && r2 < KPTS) emit_pt(inst, m2, r2, pts, out);
    if (tid + 768 < sc && r3 < KPTS) emit_pt(inst, m3, r3, pts, out);
  }
  grid_barrier(bar, 1, bid);

  // ===== stage 3: trilinear sampling, one wave per (inst, point) =====
  {
    int w = bid * 4 + (tid >> 6);                 // 0..2047
    int inst = w >> 9, kp = w & 511;
    int m = inst >> 1, b = inst & 1;
    int lane = tid & 63;                          // channel 0..63
    int idx = (int)cld32((const u32*)(pts + inst * KPTS + kp));
    int x = idx & 63, y = (idx >> 6) & 63, z = idx >> 12;
    float gx = ((float)x * 2.0f) / 63.0f - 1.0f;
    float gy = ((float)y * 2.0f) / 63.0f - 1.0f;
    float gz = ((float)z * 2.0f) / 63.0f - 1.0f;
    float ix = ((gx + 1.0f) * 64.0f - 1.0f) * 0.5f;
    float iy = ((gy + 1.0f) * 64.0f - 1.0f) * 0.5f;
    float iz = ((gz + 1.0f) * 64.0f - 1.0f) * 0.5f;
    float x0f = floorf(ix), y0f = floorf(iy), z0f = floorf(iz);
    float fx = ix - x0f, fy = iy - y0f, fz = iz - z0f;
    int x0 = (int)x0f, y0 = (int)y0f, z0 = (int)z0f;
    int xc = x0 < 0 ? 0 : (x0 > 62 ? 62 : x0);
    bool xlo = (x0 == xc);
    float wx0 = (x0 >= 0) ? (1.0f - fx) : 0.0f;
    float wx1 = (x0 <= 62) ? fx : 0.0f;
    int yc0 = y0 < 0 ? 0 : y0, yc1 = (y0 + 1) > 63 ? 63 : (y0 + 1);
    int zc0 = z0 < 0 ? 0 : z0, zc1 = (z0 + 1) > 63 ? 63 : (z0 + 1);
    float wy0 = (y0 >= 0) ? (1.0f - fy) : 0.0f;
    float wy1 = ((y0 + 1) <= 63) ? fy : 0.0f;
    float wz0 = (z0 >= 0) ? (1.0f - fz) : 0.0f;
    float wz1 = ((z0 + 1) <= 63) ? fz : 0.0f;

    const float* fv = (m ? f2 : f1) + ((size_t)b * 64 + lane) * VOX;
    float acc = 0.0f;
    #pragma unroll
    for (int dz = 0; dz < 2; dz++) {
      int zz = dz ? zc1 : zc0; float wzz = dz ? wz1 : wz0;
      #pragma unroll
      for (int dy = 0; dy < 2; dy++) {
        int yy = dy ? yc1 : yc0; float wyy = dy ? wy1 : wy0;
        f2a v = *reinterpret_cast<const f2a*>(fv + ((zz << 12) | (yy << 6) | xc));
        float v0 = xlo ? v.x : v.y;
        float v1 = xlo ? v.y : v.x;
        acc = fmaf(wzz * wyy, fmaf(v0, wx0, v1 * wx1), acc);
      }
    }
    cstf(&desc[((size_t)inst * KPTS + kp) * 64 + lane], acc);  // coalesced 4B/lane
    float ss = acc * acc;
    #pragma unroll
    for (int o = 32; o; o >>= 1) ss += __shfl_xor(ss, o);
    const float* kv = (m ? k2 : k1) + (size_t)b * VOX;
    float part = 0.0f;
    if (lane < 4) {
      int dz = lane >> 1, dy = lane & 1;
      int zz = dz ? zc1 : zc0; float wzz = dz ? wz1 : wz0;
      int yy = dy ? yc1 : yc0; float wyy = dy ? wy1 : wy0;
      f2a v = *reinterpret_cast<const f2a*>(kv + ((zz << 12) | (yy << 6) | xc));
      float v0 = xlo ? v.x : v.y;
      float v1 = xlo ? v.y : v.x;
      part = wzz * wyy * fmaf(v0, wx0, v1 * wx1);
    }
    part += __shfl_xor(part, 1);
    part += __shfl_xor(part, 2);
    if (lane == 0) {
      cstf(&norms[inst * KPTS + kp], sqrtf(ss));
      out[6144 + m * 1024 + b * KPTS + kp] = part;
    }
  }
  grid_barrier(bar, 2, bid);

  // ===== stage 4: matcher, one 32x32 (i,j) tile per block =====
  {
    float (*e0t)[68] = (float (*)[68])smem;             // 8704B
    float (*e1t)[68] = (float (*)[68])(smem + 8704);    // 8704B
    float (*d2t)[68] = (float (*)[68])(smem + 17408);   // 8704B
    float* n1s = (float*)(smem + 26112);                // 128B
    float* n2s = (float*)(smem + 26240);                // 128B
    int b = bid >> 8, ti = (bid >> 4) & 15, tj = bid & 15;
    int i0 = ti * 32, j0 = tj * 32;
    const float* d1 = desc + (size_t)b * KPTS * 64;
    const float* d2 = desc + (size_t)(2 + b) * KPTS * 64;
    {
      int row = tid >> 3, ci = (tid & 7) * 8;
      const u64* p1 = (const u64*)(d1 + (size_t)(i0 + row) * 64 + ci);
      const u64* p2 = (const u64*)(d2 + (size_t)(j0 + row) * 64 + ci);
      float a[8], c[8];
      #pragma unroll
      for (int q = 0; q < 4; q++) {
        u64 v = cld64(p1 + q);
        a[2 * q]     = __uint_as_float((u32)v);
        a[2 * q + 1] = __uint_as_float((u32)(v >> 32));
        u64 w = cld64(p2 + q);
        c[2 * q]     = __uint_as_float((u32)w);
        c[2 * q + 1] = __uint_as_float((u32)(w >> 32));
      }
      #pragma unroll
      for (int k = 0; k < 8; k++) {
        float w0 = fc_w[ci + k], w1 = fc_w[64 + ci + k];  // plain (read-only input)
        e0t[row][ci + k] = a[k] * w0;
        e1t[row][ci + k] = a[k] * w1;
        d2t[row][ci + k] = c[k];
      }
    }
    if (tid < 32) n1s[tid] = cldf(&norms[b * KPTS + i0 + tid]);
    else if (tid < 64) n2s[tid - 32] = cldf(&norms[(2 + b) * KPTS + j0 + (tid - 32)]);
    __syncthreads();
    int j = tid & 31, r0w = tid >> 5;
    float bb0 = fc_b[0], bb1 = fc_b[1];
    float s0a[4] = {0, 0, 0, 0}, s1a[4] = {0, 0, 0, 0};
    #pragma unroll
    for (int q = 0; q < 16; q++) {
      float4 D = *(const float4*)&d2t[j][q * 4];
      #pragma unroll
      for (int r = 0; r < 4; r++) {
        int i = r0w + r * 8;
        float4 E0 = *(const float4*)&e0t[i][q * 4];
        float4 E1 = *(const float4*)&e1t[i][q * 4];
        s0a[r] = fmaf(E0.x, D.x, s0a[r]); s0a[r] = fmaf(E0.y, D.y, s0a[r]);
        s0a[r] = fmaf(E0.z, D.z, s0a[r]); s0a[r] = fmaf(E0.w, D.w, s0a[r]);
        s1a[r] = fmaf(E1.x, D.x, s1a[r]); s1a[r] = fmaf(E1.y, D.y, s1a[r]);
        s1a[r] = fmaf(E1.z, D.z, s1a[r]); s1a[r] = fmaf(E1.w, D.w, s1a[r]);
      }
    }
    float n2 = n2s[j];
    #pragma unroll
    for (int r = 0; r < 4; r++) {
      int i = r0w + r * 8;
      int gi = i0 + i, gj = j0 + j;
      size_t row = ((size_t)(b * KPTS + gi)) * KPTS + gj;
      *(float2*)(out + 8192 + row * 2) = make_float2(s0a[r] + bb0, s1a[r] + bb1);
      float n1 = n1s[i];
      out[1056768 + row] = n1 * fabsf(1.0f / (1e-6f + n1) - 1.0f / (1e-6f + n2));
    }
  }
}

extern "C" void kernel_launch(void* const* d_in, const int* in_sizes, int n_in,
                              void* d_out, int out_size, void* d_ws, size_t ws_size,
                              hipStream_t stream) {
  const float* k1 = (const float*)d_in[0];
  const float* k2 = (const float*)d_in[1];
  const float* f1 = (const float*)d_in[2];
  const float* f2 = (const float*)d_in[3];
  const float* fw = (const float*)d_in[4];
  const float* fb = (const float*)d_in[5];
  float* out = (float*)d_out;
  char* ws = (char*)d_ws;
  // ws: cands(512KB) | pts(8KB) | norms(8KB) | desc(512KB) | barrier(8KB)
  u64* cands   = (u64*)ws;
  int* pts     = (int*)(ws + 524288);
  float* norms = (float*)(ws + 524288 + 8192);
  float* desc  = (float*)(ws + 524288 + 8192 + 8192);
  u32* bar     = (u32*)(ws + 1064960);

  hipMemsetAsync(bar, 0, 8192, stream);   // zero barrier counters each replay

  void* args[] = { (void*)&k1, (void*)&k2, (void*)&f1, (void*)&f2,
                   (void*)&fw, (void*)&fb, (void*)&out,
                   (void*)&cands, (void*)&pts, (void*)&norms, (void*)&desc,
                   (void*)&bar };
  hipLaunchCooperativeKernel((const void*)fused_all, dim3(GRID), dim3(256),
                             args, 0, stream);
}

// Round 8
// 72.124 us; speedup vs baseline: 3.5934x; 1.5122x over previous
//
#include <hip/hip_runtime.h>
#include <math.h>

#define KPTS 512
#define VOX (64*64*64)
#define NBLK 4096            // 16x16x16 NMS blocks per instance, 1 slot each
#define OVF 1024             // overflow (tie) slots per instance
#define NSEL 1024
#define GRID 512
#define NGRP 16
#define GSZ (GRID / NGRP)    // 32 blocks per arrival group

typedef unsigned long long u64;
typedef unsigned int u32;

typedef float f2v __attribute__((ext_vector_type(2)));
typedef f2v f2a __attribute__((aligned(4)));   // 8B vector load at 4B alignment

// ---- agent-scope coherent (LLC-coherent, XCD-safe) accessors ----
__device__ __forceinline__ void cst64(u64* p, u64 v) {
  __hip_atomic_store(p, v, __ATOMIC_RELAXED, __HIP_MEMORY_SCOPE_AGENT);
}
__device__ __forceinline__ u64 cld64(const u64* p) {
  return __hip_atomic_load(p, __ATOMIC_RELAXED, __HIP_MEMORY_SCOPE_AGENT);
}
__device__ __forceinline__ void cst32(u32* p, u32 v) {
  __hip_atomic_store(p, v, __ATOMIC_RELAXED, __HIP_MEMORY_SCOPE_AGENT);
}
__device__ __forceinline__ u32 cld32(const u32* p) {
  return __hip_atomic_load(p, __ATOMIC_RELAXED, __HIP_MEMORY_SCOPE_AGENT);
}
__device__ __forceinline__ void cstf(float* p, float v) { cst32((u32*)p, __float_as_uint(v)); }
__device__ __forceinline__ float cldf(const float* p) { return __uint_as_float(cld32((const u32*)p)); }

// f32 op-sequence sigmoid with correctly-rounded expf (via double):
// t = rn(exp(-x)); s = 1/(1+t)  -- mimics NumPy f32 semantics.
__device__ __forceinline__ float ref_sigmoid(float x) {
  float t = (float)exp(-(double)x);
  float d = 1.0f + t;
  return 1.0f / d;
}

// Fence-free hierarchical grid barrier (2 phases). Cross-stage data moves
// through agent-coherent accesses, so no L2 writeback is needed here.
// bar layout (u32 words, 64B stride): gcnt[p][g] @ (p*16+g)*16,
// root[p] @ (48+p)*16, gdone[p][g] @ (64+p*16+g)*16, ovfCnt[i] @ (100+i)*16.
// Zeroed per replay by a 16KB memset node (also covers pts sentinels).
__device__ __forceinline__ void grid_barrier(u32* bar, int phase, int bid) {
  __syncthreads();
  if (threadIdx.x == 0) {
    int g = bid & (NGRP - 1);
    u32 r = __hip_atomic_fetch_add(bar + (phase * NGRP + g) * 16, 1u,
                                   __ATOMIC_RELAXED, __HIP_MEMORY_SCOPE_AGENT);
    if (r == GSZ - 1)
      __hip_atomic_fetch_add(bar + (48 + phase) * 16, 1u,
                             __ATOMIC_RELAXED, __HIP_MEMORY_SCOPE_AGENT);
    if (bid < NGRP) {                     // announcer for group g == bid
      while (__hip_atomic_load(bar + (48 + phase) * 16, __ATOMIC_RELAXED,
                               __HIP_MEMORY_SCOPE_AGENT) < NGRP)
        __builtin_amdgcn_s_sleep(4);
      cst32(bar + (64 + phase * NGRP + g) * 16, 1u);
    } else {                              // <=31 spinners per gdone line
      while (__hip_atomic_load(bar + (64 + phase * NGRP + g) * 16,
                               __ATOMIC_RELAXED, __HIP_MEMORY_SCOPE_AGENT) == 0u)
        __builtin_amdgcn_s_sleep(4);
    }
  }
  __syncthreads();
}

__device__ __forceinline__ int key_bin(u64 key) {
  u32 vb = (u32)(key >> 32);
  return (vb >= 0x3F800000u) ? 255 : ((vb < 0x3F000000u) ? 0 : (int)((vb >> 15) & 0xFF));
}

__device__ __forceinline__ void emit_pt(int inst, u64 key, u32 rank,
                                        u32* __restrict__ pts,
                                        float* __restrict__ out) {
  u32 idx = ~(u32)key;                    // 0xFFFFFFFF - low
  cst32(pts + inst * KPTS + rank, idx + 1u);   // +1: 0 is the spin sentinel
  int x = idx & 63, y = (idx >> 6) & 63, z = (int)(idx >> 12);
  float gx = ((float)x * 2.0f) / 63.0f - 1.0f;
  float gy = ((float)y * 2.0f) / 63.0f - 1.0f;
  float gz = ((float)z * 2.0f) / 63.0f - 1.0f;
  int m = inst >> 1, b = inst & 1;
  float* g = out + (size_t)m * 3072 + (size_t)(b * KPTS + rank) * 3;
  g[0] = gx; g[1] = gy; g[2] = gz;        // out: host-read only, plain stores
}

// Whole pipeline in one cooperative kernel: NMS -> top-512 -> sample -> match.
// 512 blocks x 256 threads; 2 barriers + pts-dataflow for stage2->stage3.
__global__ void __launch_bounds__(256, 2) fused_all(
    const float* __restrict__ k1, const float* __restrict__ k2,
    const float* __restrict__ f1, const float* __restrict__ f2,
    const float* __restrict__ fc_w, const float* __restrict__ fc_b,
    float* __restrict__ out, u64* __restrict__ cands, u64* __restrict__ ovf,
    u32* __restrict__ pts, float* __restrict__ norms, float* __restrict__ desc,
    u32* __restrict__ bar)
{
  __shared__ __align__(16) char smem[26624];
  int bid = blockIdx.x, tid = threadIdx.x;

  // ===== stage 1: sigmoid + 4x4x4 NMS; 1 slot/block + tie overflow =====
  {
    float (*sm)[16] = (float (*)[16])smem;        // 256B
    u32* wcnt = (u32*)(smem + 256);               // 64B
    for (int u = bid; u < 1024; u += GRID) {      // 2 strip-units per block
      int strip = u & 255, inst = u >> 8;
      const float* vol = ((inst >> 1) ? k2 : k1) + (size_t)(inst & 1) * VOX;
      __syncthreads();                            // LDS reuse across iters
      if (tid < 16) wcnt[tid] = 0;
      int x = tid & 63, yl = tid >> 6;
      int yb = strip & 15, zb = strip >> 4;
      int y = yb * 4 + yl, z0 = zb * 4;
      float s[4];
      #pragma unroll
      for (int zl = 0; zl < 4; zl++)
        s[zl] = ref_sigmoid(vol[((z0 + zl) << 12) | (y << 6) | x]);
      float m = fmaxf(fmaxf(s[0], s[1]), fmaxf(s[2], s[3]));
      m = fmaxf(m, __shfl_xor(m, 1));
      m = fmaxf(m, __shfl_xor(m, 2));             // max over 4x * 1y * 4z
      if ((x & 3) == 0) sm[yl][x >> 2] = m;
      __syncthreads();
      int xb = x >> 2;
      float bm = fmaxf(fmaxf(sm[0][xb], sm[1][xb]), fmaxf(sm[2][xb], sm[3][xb]));
      int nb = ((zb * 16 + yb) << 4) | xb;
      #pragma unroll
      for (int zl = 0; zl < 4; zl++) {
        if (s[zl] == bm) {                        // winner (all ties emitted)
          int addr = ((z0 + zl) << 12) | (y << 6) | x;
          u64 key = ((u64)__float_as_uint(s[zl]) << 32) | (u64)(0xFFFFFFFFu - (u32)addr);
          u32 r = atomicAdd(&wcnt[xb], 1u);       // LDS atomic, ~1/block
          if (r == 0) {                           // slot occupant (set-determinism)
            cst64(&cands[(size_t)inst * NBLK + nb], key);
          } else {                                // rare tie -> global overflow
            u32 p = __hip_atomic_fetch_add(bar + (100 + inst) * 16, 1u,
                                           __ATOMIC_RELAXED, __HIP_MEMORY_SCOPE_AGENT);
            if (p < OVF) cst64(&ovf[(size_t)inst * OVF + p], key);
          }
        }
      }
    }
  }
  grid_barrier(bar, 0, bid);

  // ===== stage 2: per-instance top-512 (histogram prune + rank) =====
  if (bid < 4) {
    int inst = bid;
    u64* sel    = (u64*)smem;                     // 8192B
    u32* hist   = (u32*)(smem + 8192);            // 1024B
    u32* selCnt = (u32*)(smem + 9216);
    int* bstar  = (int*)(smem + 9220);
    hist[tid] = 0;
    if (tid == 0) *selCnt = 0;
    __syncthreads();
    const u64* cb = cands + (size_t)inst * NBLK;  // all 4096 valid
    const u64* ob = ovf + (size_t)inst * OVF;
    u32 ov = cld32(bar + (100 + inst) * 16); if (ov > OVF) ov = OVF;
    // pass 1: histogram (batched 8-deep coherent loads)
    for (int g = 0; g < 2; g++) {
      u64 k8[8];
      #pragma unroll
      for (int q = 0; q < 8; q++) k8[q] = cld64(cb + tid + (g * 8 + q) * 256);
      #pragma unroll
      for (int q = 0; q < 8; q++) atomicAdd(&hist[key_bin(k8[q])], 1u);
    }
    for (u32 i = tid; i < ov; i += 256) atomicAdd(&hist[key_bin(cld64(ob + i))], 1u);
    __syncthreads();
    if (tid == 0) {
      u32 cum = 0; int b = 255;
      for (; b >= 0; b--) { cum += hist[b]; if (cum >= KPTS) break; }
      *bstar = (b < 0) ? 0 : b;
    }
    __syncthreads();
    int B = *bstar;
    // pass 2: append survivors (per-thread LDS atomic, no ballot)
    for (int g = 0; g < 2; g++) {
      u64 k8[8];
      #pragma unroll
      for (int q = 0; q < 8; q++) k8[q] = cld64(cb + tid + (g * 8 + q) * 256);
      #pragma unroll
      for (int q = 0; q < 8; q++) {
        if (key_bin(k8[q]) >= B) {
          u32 p = atomicAdd(selCnt, 1u);
          if (p < NSEL) sel[p] = k8[q];
        }
      }
    }
    for (u32 i = tid; i < ov; i += 256) {
      u64 key = cld64(ob + i);
      if (key_bin(key) >= B) {
        u32 p = atomicAdd(selCnt, 1u);
        if (p < NSEL) sel[p] = key;
      }
    }
    __syncthreads();
    u32 sc = *selCnt; if (sc > NSEL) sc = NSEL;
    // rank by broadcast scan: (value desc, idx asc) == u64 desc; keys unique;
    // rank is independent of sel[] order -> deterministic output.
    u64 m0 = (tid < sc) ? sel[tid] : 0ull;
    u64 m1 = (tid + 256 < sc) ? sel[tid + 256] : 0ull;
    u64 m2 = (tid + 512 < sc) ? sel[tid + 512] : 0ull;
    u64 m3 = (tid + 768 < sc) ? sel[tid + 768] : 0ull;
    u32 r0 = 0, r1 = 0, r2 = 0, r3 = 0;
    for (u32 i = 0; i < sc; i++) {
      u64 v = sel[i];                             // LDS broadcast (same addr)
      r0 += (v > m0); r1 += (v > m1); r2 += (v > m2); r3 += (v > m3);
    }
    if (tid < sc && r0 < KPTS) emit_pt(inst, m0, r0, pts, out);
    if (tid + 256 < sc && r1 < KPTS) emit_pt(inst, m1, r1, pts, out);
    if (tid + 512 < sc && r2 < KPTS) emit_pt(inst, m2, r2, pts, out);
    if (tid + 768 < sc && r3 < KPTS) emit_pt(inst, m3, r3, pts, out);
  }
  // no barrier: stage 3 spins on its own pts dword (dataflow sync)

  // ===== stage 3: trilinear sampling, one wave per (inst, point) =====
  {
    int w = bid * 4 + (tid >> 6);                 // 0..2047
    int inst = w >> 9, kp = w & 511;
    int m = inst >> 1, b = inst & 1;
    int lane = tid & 63;                          // channel 0..63
    const u32* pp = pts + inst * KPTS + kp;
    u32 v;
    while ((v = cld32(pp)) == 0u) __builtin_amdgcn_s_sleep(2);
    int idx = (int)(v - 1u);
    int x = idx & 63, y = (idx >> 6) & 63, z = idx >> 12;
    float gx = ((float)x * 2.0f) / 63.0f - 1.0f;
    float gy = ((float)y * 2.0f) / 63.0f - 1.0f;
    float gz = ((float)z * 2.0f) / 63.0f - 1.0f;
    float ix = ((gx + 1.0f) * 64.0f - 1.0f) * 0.5f;
    float iy = ((gy + 1.0f) * 64.0f - 1.0f) * 0.5f;
    float iz = ((gz + 1.0f) * 64.0f - 1.0f) * 0.5f;
    float x0f = floorf(ix), y0f = floorf(iy), z0f = floorf(iz);
    float fx = ix - x0f, fy = iy - y0f, fz = iz - z0f;
    int x0 = (int)x0f, y0 = (int)y0f, z0 = (int)z0f;
    int xc = x0 < 0 ? 0 : (x0 > 62 ? 62 : x0);
    bool xlo = (x0 == xc);
    float wx0 = (x0 >= 0) ? (1.0f - fx) : 0.0f;
    float wx1 = (x0 <= 62) ? fx : 0.0f;
    int yc0 = y0 < 0 ? 0 : y0, yc1 = (y0 + 1) > 63 ? 63 : (y0 + 1);
    int zc0 = z0 < 0 ? 0 : z0, zc1 = (z0 + 1) > 63 ? 63 : (z0 + 1);
    float wy0 = (y0 >= 0) ? (1.0f - fy) : 0.0f;
    float wy1 = ((y0 + 1) <= 63) ? fy : 0.0f;
    float wz0 = (z0 >= 0) ? (1.0f - fz) : 0.0f;
    float wz1 = ((z0 + 1) <= 63) ? fz : 0.0f;

    const float* fv = (m ? f2 : f1) + ((size_t)b * 64 + lane) * VOX;
    float acc = 0.0f;
    #pragma unroll
    for (int dz = 0; dz < 2; dz++) {
      int zz = dz ? zc1 : zc0; float wzz = dz ? wz1 : wz0;
      #pragma unroll
      for (int dy = 0; dy < 2; dy++) {
        int yy = dy ? yc1 : yc0; float wyy = dy ? wy1 : wy0;
        f2a vv = *reinterpret_cast<const f2a*>(fv + ((zz << 12) | (yy << 6) | xc));
        float v0 = xlo ? vv.x : vv.y;
        float v1 = xlo ? vv.y : vv.x;
        acc = fmaf(wzz * wyy, fmaf(v0, wx0, v1 * wx1), acc);
      }
    }
    cstf(&desc[((size_t)inst * KPTS + kp) * 64 + lane], acc);  // coalesced
    float ss = acc * acc;
    #pragma unroll
    for (int o = 32; o; o >>= 1) ss += __shfl_xor(ss, o);
    const float* kv = (m ? k2 : k1) + (size_t)b * VOX;
    float part = 0.0f;
    if (lane < 4) {
      int dz = lane >> 1, dy = lane & 1;
      int zz = dz ? zc1 : zc0; float wzz = dz ? wz1 : wz0;
      int yy = dy ? yc1 : yc0; float wyy = dy ? wy1 : wy0;
      f2a vv = *reinterpret_cast<const f2a*>(kv + ((zz << 12) | (yy << 6) | xc));
      float v0 = xlo ? vv.x : vv.y;
      float v1 = xlo ? vv.y : vv.x;
      part = wzz * wyy * fmaf(v0, wx0, v1 * wx1);
    }
    part += __shfl_xor(part, 1);
    part += __shfl_xor(part, 2);
    if (lane == 0) {
      cstf(&norms[inst * KPTS + kp], sqrtf(ss));
      out[6144 + m * 1024 + b * KPTS + kp] = part;
    }
  }
  grid_barrier(bar, 1, bid);

  // ===== stage 4: matcher, one 32x32 (i,j) tile per block =====
  {
    float (*e0t)[68] = (float (*)[68])smem;             // 8704B
    float (*e1t)[68] = (float (*)[68])(smem + 8704);    // 8704B
    float (*d2t)[68] = (float (*)[68])(smem + 17408);   // 8704B
    float* n1s = (float*)(smem + 26112);                // 128B
    float* n2s = (float*)(smem + 26240);                // 128B
    int b = bid >> 8, ti = (bid >> 4) & 15, tj = bid & 15;
    int i0 = ti * 32, j0 = tj * 32;
    const float* d1 = desc + (size_t)b * KPTS * 64;
    const float* d2 = desc + (size_t)(2 + b) * KPTS * 64;
    {
      int row = tid >> 3, ci = (tid & 7) * 8;
      const u64* p1 = (const u64*)(d1 + (size_t)(i0 + row) * 64 + ci);
      const u64* p2 = (const u64*)(d2 + (size_t)(j0 + row) * 64 + ci);
      float a[8], c[8];
      #pragma unroll
      for (int q = 0; q < 4; q++) {
        u64 v = cld64(p1 + q);
        a[2 * q]     = __uint_as_float((u32)v);
        a[2 * q + 1] = __uint_as_float((u32)(v >> 32));
        u64 w = cld64(p2 + q);
        c[2 * q]     = __uint_as_float((u32)w);
        c[2 * q + 1] = __uint_as_float((u32)(w >> 32));
      }
      #pragma unroll
      for (int k = 0; k < 8; k++) {
        float w0 = fc_w[ci + k], w1 = fc_w[64 + ci + k];  // read-only input
        e0t[row][ci + k] = a[k] * w0;
        e1t[row][ci + k] = a[k] * w1;
        d2t[row][ci + k] = c[k];
      }
    }
    if (tid < 32) n1s[tid] = cldf(&norms[b * KPTS + i0 + tid]);
    else if (tid < 64) n2s[tid - 32] = cldf(&norms[(2 + b) * KPTS + j0 + (tid - 32)]);
    __syncthreads();
    int j = tid & 31, r0w = tid >> 5;
    float bb0 = fc_b[0], bb1 = fc_b[1];
    float s0a[4] = {0, 0, 0, 0}, s1a[4] = {0, 0, 0, 0};
    #pragma unroll
    for (int q = 0; q < 16; q++) {
      float4 D = *(const float4*)&d2t[j][q * 4];
      #pragma unroll
      for (int r = 0; r < 4; r++) {
        int i = r0w + r * 8;
        float4 E0 = *(const float4*)&e0t[i][q * 4];
        float4 E1 = *(const float4*)&e1t[i][q * 4];
        s0a[r] = fmaf(E0.x, D.x, s0a[r]); s0a[r] = fmaf(E0.y, D.y, s0a[r]);
        s0a[r] = fmaf(E0.z, D.z, s0a[r]); s0a[r] = fmaf(E0.w, D.w, s0a[r]);
        s1a[r] = fmaf(E1.x, D.x, s1a[r]); s1a[r] = fmaf(E1.y, D.y, s1a[r]);
        s1a[r] = fmaf(E1.z, D.z, s1a[r]); s1a[r] = fmaf(E1.w, D.w, s1a[r]);
      }
    }
    float n2 = n2s[j];
    #pragma unroll
    for (int r = 0; r < 4; r++) {
      int i = r0w + r * 8;
      int gi = i0 + i, gj = j0 + j;
      size_t row = ((size_t)(b * KPTS + gi)) * KPTS + gj;
      *(float2*)(out + 8192 + row * 2) = make_float2(s0a[r] + bb0, s1a[r] + bb1);
      float n1 = n1s[i];
      out[1056768 + row] = n1 * fabsf(1.0f / (1e-6f + n1) - 1.0f / (1e-6f + n2));
    }
  }
}

extern "C" void kernel_launch(void* const* d_in, const int* in_sizes, int n_in,
                              void* d_out, int out_size, void* d_ws, size_t ws_size,
                              hipStream_t stream) {
  const float* k1 = (const float*)d_in[0];
  const float* k2 = (const float*)d_in[1];
  const float* f1 = (const float*)d_in[2];
  const float* f2 = (const float*)d_in[3];
  const float* fw = (const float*)d_in[4];
  const float* fb = (const float*)d_in[5];
  float* out = (float*)d_out;
  char* ws = (char*)d_ws;
  // ws: [bar 8KB | pts 8KB] (memset 0 each replay) | cands 128KB | ovf 32KB
  //     | norms 8KB | desc 512KB
  u32* bar     = (u32*)ws;
  u32* pts     = (u32*)(ws + 8192);
  u64* cands   = (u64*)(ws + 16384);
  u64* ovf     = (u64*)(ws + 16384 + 131072);
  float* norms = (float*)(ws + 180224);
  float* desc  = (float*)(ws + 188416);

  hipMemsetAsync(ws, 0, 16384, stream);   // barrier counters + pts sentinels

  void* args[] = { (void*)&k1, (void*)&k2, (void*)&f1, (void*)&f2,
                   (void*)&fw, (void*)&fb, (void*)&out,
                   (void*)&cands, (void*)&ovf, (void*)&pts,
                   (void*)&norms, (void*)&desc, (void*)&bar };
  hipLaunchCooperativeKernel((const void*)fused_all, dim3(GRID), dim3(256),
                             args, 0, stream);
}